// Round 1
// baseline (206.935 us; speedup 1.0000x reference)
//
#include <hip/hip_runtime.h>

// OuterProductNetworkLayer: out[b,n] = sum_{h,e} emb[b,row(n),e] * K[h,n,e] * emb[b,col(n),h]
// B=2048, NUM_FIELDS=32, EMBED=64, P=496.
// Round 1: fp32 baseline. W_n held in VGPRs per wave (lane=h, 64 regs),
// p broadcast via scalar loads (wave-uniform b), q coalesced vector load.

#define B_TOT 2048
#define NF    32
#define EMB   64
#define NP    496   // NF*(NF-1)/2
#define BT    512   // batch tile per block

__global__ __launch_bounds__(256) void opnl_kernel(
    const float* __restrict__ emb,   // [B, NF, EMB]
    const float* __restrict__ kern,  // [EMB(h), NP, EMB(e)]
    float* __restrict__ out)         // [B, NP]
{
    const int n     = blockIdx.x % NP;
    const int btile = blockIdx.x / NP;

    // decode (row, col) for pair index n  (np.triu_indices order)
    int r = 0, rem = n;
    while (rem >= NF - 1 - r) { rem -= NF - 1 - r; ++r; }
    const int row = r;
    const int col = r + 1 + rem;

    // Stage W_n^T into LDS: Wt[e*65 + h] = kern[h, n, e].
    // Global read coalesced (contiguous e per wave); +1 pad makes both the
    // transpose store (banks = (e + h) % 32) and the register read conflict-free.
    __shared__ float Wt[EMB * 65];
    for (int idx = threadIdx.x; idx < EMB * EMB; idx += 256) {
        const int h = idx >> 6;
        const int e = idx & 63;
        Wt[e * 65 + h] = kern[((size_t)h * NP + n) * EMB + e];
    }
    __syncthreads();

    const int lane = threadIdx.x & 63;   // lane = h
    const int wid  = threadIdx.x >> 6;   // 4 waves

    float w[EMB];
#pragma unroll
    for (int e = 0; e < EMB; ++e) w[e] = Wt[e * 65 + lane];

    const int b0 = btile * BT;
    for (int bi = wid; bi < BT; bi += 4) {
        // b is wave-uniform by construction; make it provable -> scalar loads for p
        const int b = __builtin_amdgcn_readfirstlane(b0 + bi);
        const float* __restrict__ pv = emb + ((size_t)b * NF + row) * EMB;
        const float* __restrict__ qv = emb + ((size_t)b * NF + col) * EMB;

        const float qval = qv[lane];     // coalesced 256B vector load

        float t0 = 0.f, t1 = 0.f, t2 = 0.f, t3 = 0.f;
#pragma unroll
        for (int e = 0; e < EMB; e += 4) {
            t0 = fmaf(w[e + 0], pv[e + 0], t0);   // pv[e]: SGPR broadcast
            t1 = fmaf(w[e + 1], pv[e + 1], t1);
            t2 = fmaf(w[e + 2], pv[e + 2], t2);
            t3 = fmaf(w[e + 3], pv[e + 3], t3);
        }
        float val = ((t0 + t1) + (t2 + t3)) * qval;   // t[h] * q[h], h = lane

        // wave-wide sum over h
#pragma unroll
        for (int off = 32; off > 0; off >>= 1)
            val += __shfl_down(val, off, 64);

        if (lane == 0) out[(size_t)b * NP + n] = val;
    }
}

extern "C" void kernel_launch(void* const* d_in, const int* in_sizes, int n_in,
                              void* d_out, int out_size, void* d_ws, size_t ws_size,
                              hipStream_t stream) {
    const float* emb  = (const float*)d_in[0];   // 2048*32*64
    const float* kern = (const float*)d_in[1];   // 64*496*64
    float*       out  = (float*)d_out;           // 2048*496

    const int grid = NP * (B_TOT / BT);          // 496 * 4 = 1984 blocks
    opnl_kernel<<<grid, 256, 0, stream>>>(emb, kern, out);
}

// Round 2
// 78.308 us; speedup vs baseline: 2.6426x; 2.6426x over previous
//
#include <hip/hip_runtime.h>

// OuterProductNetworkLayer via MFMA:
//   out[b,n] = q_b^T W_n p_b,  W_n = kern[:, n, :]  (64x64)
// Per wave, fixed n: U[h, b] = sum_e W[h,e] p[b,e] via mfma_f32_16x16x32_bf16
//   A = W   (M=h 16-tile, K=e)    lane: row=l&15, k=(l>>4)*8+j (+32*kc)
//   B = p^T (K=e, N=b 16-tile)    lane: col=l&15, k=(l>>4)*8+j (+32*kc)
//   D layout (verified, learn_hip m89): col=lane&15 (=b), row=(lane>>4)*4+reg (=h)
// Then out[b] = sum_h U[h,b] * q[b,h] : in-lane fp32 fma over 16 regs (q as float4),
// reduce over 4 lanes sharing b via shfl_xor(16), shfl_xor(32).
// W fragments live in VGPRs (32) and are reused across 128 b's per wave.

#define B_TOT 2048
#define NF    32
#define EMB   64
#define NP    496
#define NBG   16                 // b-groups per n -> jobs = 496*16 = 7936 waves
#define TPJ   (B_TOT / NBG / 16) // 8 b-tiles of 16 per job

typedef short bf16x8 __attribute__((ext_vector_type(8)));
typedef float f32x4  __attribute__((ext_vector_type(4)));

static __device__ inline short f2bf(float f) {     // RNE fp32 -> bf16
    unsigned u = __builtin_bit_cast(unsigned, f);
    u += 0x7fffu + ((u >> 16) & 1u);
    return (short)(u >> 16);
}

__global__ __launch_bounds__(256) void opnl_mfma(
    const float* __restrict__ emb,   // [B, NF, EMB] f32
    const float* __restrict__ kern,  // [EMB(h), NP, EMB(e)] f32
    float* __restrict__ out)         // [B, NP] f32
{
    const int job = blockIdx.x * 4 + (threadIdx.x >> 6);
    const int n   = job / NBG;       // 4 waves of a block share n (W L1-reuse)
    const int bg  = job % NBG;

    // decode (row, col) of pair n (np.triu_indices order)
    int r = 0, rem = n;
    while (rem >= NF - 1 - r) { rem -= NF - 1 - r; ++r; }
    const int row = r;
    const int col = r + 1 + rem;

    const int lane = threadIdx.x & 63;
    const int lo4  = lane & 15;      // b' (N) / h' (A-row)
    const int hi4  = lane >> 4;      // 0..3

    // ---- W_n fragments: wfrag[mh][kc], h = mh*16 + lo4, e = kc*32 + hi4*8 + j
    bf16x8 wfrag[4][2];
#pragma unroll
    for (int mh = 0; mh < 4; ++mh) {
        const int h = mh * 16 + lo4;
        const float* wr = kern + ((size_t)h * NP + n) * EMB + hi4 * 8;
#pragma unroll
        for (int kc = 0; kc < 2; ++kc) {
#pragma unroll
            for (int j = 0; j < 8; ++j)
                wfrag[mh][kc][j] = f2bf(wr[kc * 32 + j]);
        }
    }

    const int b_lane0 = bg * (B_TOT / NBG);   // this job's first b

    for (int t = 0; t < TPJ; ++t) {
        const int b = b_lane0 + t * 16 + lo4;
        const float* pe = emb + ((size_t)b * NF + row) * EMB;
        const float* qe = emb + ((size_t)b * NF + col) * EMB;

        // B fragments: p[b, e], e = kc*32 + hi4*8 + j
        bf16x8 pfrag[2];
#pragma unroll
        for (int kc = 0; kc < 2; ++kc) {
            const float* ps = pe + kc * 32 + hi4 * 8;
#pragma unroll
            for (int j = 0; j < 8; ++j) pfrag[kc][j] = f2bf(ps[j]);
        }

        f32x4 acc[4] = {f32x4{0,0,0,0}, f32x4{0,0,0,0},
                        f32x4{0,0,0,0}, f32x4{0,0,0,0}};
#pragma unroll
        for (int mh = 0; mh < 4; ++mh)
#pragma unroll
            for (int kc = 0; kc < 2; ++kc)
                acc[mh] = __builtin_amdgcn_mfma_f32_16x16x32_bf16(
                    wfrag[mh][kc], pfrag[kc], acc[mh], 0, 0, 0);

        // out[b] = sum_h U[h,b] * q[b,h] ; lane holds h = mh*16 + hi4*4 + r
        float val = 0.f;
#pragma unroll
        for (int mh = 0; mh < 4; ++mh) {
            const f32x4 qv = *(const f32x4*)(qe + mh * 16 + hi4 * 4);
            val += acc[mh][0] * qv[0] + acc[mh][1] * qv[1]
                 + acc[mh][2] * qv[2] + acc[mh][3] * qv[3];
        }
        val += __shfl_xor(val, 16, 64);
        val += __shfl_xor(val, 32, 64);
        if (lane < 16) out[(size_t)b * NP + n] = val;
    }
}

extern "C" void kernel_launch(void* const* d_in, const int* in_sizes, int n_in,
                              void* d_out, int out_size, void* d_ws, size_t ws_size,
                              hipStream_t stream) {
    const float* emb  = (const float*)d_in[0];
    const float* kern = (const float*)d_in[1];
    float*       out  = (float*)d_out;

    const int grid = NP * NBG / 4;   // 1984 blocks x 256 threads (4 waves)
    opnl_mfma<<<grid, 256, 0, stream>>>(emb, kern, out);
}

// Round 3
// 77.409 us; speedup vs baseline: 2.6733x; 1.0116x over previous
//
#include <hip/hip_runtime.h>

// out[b,n] = q^T W_n p, p=emb[b,row(n)], q=emb[b,col(n)], W_n=kern[:,n,:]
// Plan: prep kernel converts kern -> bf16 [n][h][e] in d_ws.
// Main: block = 4 waves, owns 16 b's; stages emb[b-tile, all 32 fields] as
// bf16 in LDS (72KB) once; waves sweep 31 n's each (124 per block, n-chunk
// pinned per XCD so the 1MB W-window stays L2-resident). W double-buffered
// in registers; inner loop = coalesced W loads + LDS reads + 8 MFMA, no bar.

#define B_TOT 2048
#define NF    32
#define EMB   64
#define NP    496
#define BT    16            // b per block
#define NCHK  4             // n chunks (one per XCD pair)
#define NPC   (NP / NCHK)   // 124 n per chunk
#define NPW   (NPC / 4)     // 31 n per wave
#define ESTR  72            // LDS row stride in bf16 elems (pad: 64+8)

typedef short bf16x8 __attribute__((ext_vector_type(8)));
typedef short bf16x4 __attribute__((ext_vector_type(4)));
typedef float f32x4  __attribute__((ext_vector_type(4)));

static __device__ inline unsigned f2bf(float f) {          // RNE f32->bf16
    unsigned u = __builtin_bit_cast(unsigned, f);
    u += 0x7fffu + ((u >> 16) & 1u);
    return u >> 16;
}
static __device__ inline unsigned pack2(float lo, float hi) {
    return f2bf(lo) | (f2bf(hi) << 16);
}
static __device__ inline float bf2f(short s) {
    return __builtin_bit_cast(float, (unsigned)((unsigned short)s) << 16);
}

// ---- prep: kern f32 [h][n][e] -> bf16 [n][h][e] (contiguous 8KB per n)
__global__ __launch_bounds__(256) void cvt_kernel(const float* __restrict__ kern,
                                                  unsigned* __restrict__ kb) {
    const int i = (blockIdx.x * 256 + threadIdx.x) * 4;    // [n][h][e] elem idx
    const int n = i >> 12, h = (i >> 6) & 63, e = i & 63;
    const f32x4 v = *(const f32x4*)(kern + ((size_t)h * NP + n) * EMB + e);
    uint2 w;
    w.x = pack2(v[0], v[1]);
    w.y = pack2(v[2], v[3]);
    *(uint2*)(kb + (i >> 1)) = w;
}

__global__ __launch_bounds__(256) void opnl_main(
    const float* __restrict__ emb,   // [B][NF][EMB] f32
    const short* __restrict__ kb,    // [NP][64][64] bf16
    float* __restrict__ out)         // [B][NP] f32
{
    __shared__ short elds[NF * BT * ESTR];   // 32 fields x 16 b x 72 = 72KB

    // XCD-aware mapping: xcd = bid&7 -> n-chunk = xcd>>1, btile spread over j
    const int x  = blockIdx.x & 7;
    const int j  = blockIdx.x >> 3;          // 0..63
    const int nc = x >> 1;                   // 0..3
    const int b0 = (j * 2 + (x & 1)) * BT;   // 0..127 tiles of 16

    // ---- stage emb[b0..b0+15][0..31][0..63] -> bf16 LDS (once)
    {
        const int sb = threadIdx.x >> 4;          // 0..15 (b)
        const int se = (threadIdx.x & 15) * 4;    // 0..60 (e)
        const float* ebase = emb + ((size_t)(b0 + sb) * NF) * EMB + se;
        for (int f = 0; f < NF; ++f) {
            const f32x4 v = *(const f32x4*)(ebase + f * EMB);
            uint2 w;
            w.x = pack2(v[0], v[1]);
            w.y = pack2(v[2], v[3]);
            *(uint2*)&elds[f * (BT * ESTR) + sb * ESTR + se] = w;
        }
    }
    __syncthreads();

    const int lane = threadIdx.x & 63;
    const int wid  = threadIdx.x >> 6;
    const int lo4  = lane & 15;
    const int hi4  = lane >> 4;

    int n = nc * NPC + wid * NPW;
    // decode row/col of starting n (np.triu_indices order)
    int r = 0, rem = n;
    while (rem >= NF - 1 - r) { rem -= NF - 1 - r; ++r; }
    int c = r + 1 + rem;

    auto loadW = [&](bf16x8 (&wf)[4][2], int nn) {
        const bf16x8* wp = (const bf16x8*)(kb + (size_t)nn * (EMB * EMB));
#pragma unroll
        for (int mh = 0; mh < 4; ++mh)
#pragma unroll
            for (int kc = 0; kc < 2; ++kc)
                wf[mh][kc] = wp[(((mh * 16 + lo4) * 64) + kc * 32 + hi4 * 8) >> 3];
    };

    auto compute = [&](bf16x8 (&wf)[4][2], int nn, int rr, int cc) {
        bf16x8 pf[2];
#pragma unroll
        for (int kc = 0; kc < 2; ++kc)
            pf[kc] = *(const bf16x8*)&elds[rr * (BT * ESTR) + lo4 * ESTR + kc * 32 + hi4 * 8];

        f32x4 acc[4] = {f32x4{0,0,0,0}, f32x4{0,0,0,0},
                        f32x4{0,0,0,0}, f32x4{0,0,0,0}};
#pragma unroll
        for (int mh = 0; mh < 4; ++mh)
#pragma unroll
            for (int kc = 0; kc < 2; ++kc)
                acc[mh] = __builtin_amdgcn_mfma_f32_16x16x32_bf16(
                    wf[mh][kc], pf[kc], acc[mh], 0, 0, 0);

        float val = 0.f;
#pragma unroll
        for (int mh = 0; mh < 4; ++mh) {
            const bf16x4 q = *(const bf16x4*)&elds[cc * (BT * ESTR) + lo4 * ESTR + mh * 16 + hi4 * 4];
            val += acc[mh][0] * bf2f(q[0]) + acc[mh][1] * bf2f(q[1])
                 + acc[mh][2] * bf2f(q[2]) + acc[mh][3] * bf2f(q[3]);
        }
        val += __shfl_xor(val, 16, 64);
        val += __shfl_xor(val, 32, 64);
        if (lane < 16) out[(size_t)(b0 + lo4) * NP + nn] = val;
    };

#define ADV do { ++c; if (c == NF) { ++r; c = r + 1; } } while (0)

    bf16x8 wA[4][2], wB[4][2];
    loadW(wA, n);
    for (int k = 0; k < NPW / 2; ++k) {      // 15 iters, 2 n's each
        loadW(wB, n + 1);
        compute(wA, n, r, c);
        ++n; ADV;
        loadW(wA, n + 1);
        compute(wB, n, r, c);
        ++n; ADV;
    }
    compute(wA, n, r, c);                    // n = start+30
#undef ADV
}

extern "C" void kernel_launch(void* const* d_in, const int* in_sizes, int n_in,
                              void* d_out, int out_size, void* d_ws, size_t ws_size,
                              hipStream_t stream) {
    const float* emb  = (const float*)d_in[0];   // 2048*32*64
    const float* kern = (const float*)d_in[1];   // 64*496*64
    float*       out  = (float*)d_out;           // 2048*496

    unsigned* kb = (unsigned*)d_ws;              // 496*64*64 bf16 = 4MB

    // prep: 496*64*64 = 2,031,616 elems / (256*4) = 1984 blocks exactly
    cvt_kernel<<<(NP * EMB * EMB) / (256 * 4), 256, 0, stream>>>(kern, kb);

    // main: 128 b-tiles x 4 n-chunks = 512 blocks (2 per CU)
    opnl_main<<<512, 256, 0, stream>>>(emb, (const short*)kb, out);
}